// Round 6
// baseline (308.953 us; speedup 1.0000x reference)
//
#include <hip/hip_runtime.h>
#include <stdint.h>

// Problem dims (fixed by reference setup_inputs)
#define M_DIM 16384
#define N_DIM 2048
#define K_DIM 2048

// GEMM geometry: 256x256 tile, BK=64, 8 waves (2M x 4N, wave = 128x64),
// 4-deep LDS pipeline (128 KB), 4 phases per iter (2 K-tiles), counted vmcnt.
#define BM 256
#define BN 256
#define BK 64
#define NT (K_DIM / BK)          // 32 K-tiles
#define HALF_A 16384             // A region bytes per K-tile buffer (256 x 64)
#define BUF_BYTES 32768          // A 16K + B 16K
#define NBUF 4
#define SMEM_BYTES (NBUF * BUF_BYTES)   // 131072

typedef int v4i __attribute__((ext_vector_type(4)));

// ---------------------------------------------------------------------------
// Kernel 0: pack widened int32 weights -> int8
// ---------------------------------------------------------------------------
__global__ __launch_bounds__(256) void pack_w_kernel(const int* __restrict__ w32,
                                                     int8_t* __restrict__ w8) {
    const int i = (blockIdx.x * 256 + threadIdx.x) * 8;
    const int4 a = *reinterpret_cast<const int4*>(w32 + i);
    const int4 b = *reinterpret_cast<const int4*>(w32 + i + 4);
    uint32_t lo = (a.x & 255) | ((a.y & 255) << 8) | ((a.z & 255) << 16) | ((uint32_t)(a.w & 255) << 24);
    uint32_t hi = (b.x & 255) | ((b.y & 255) << 8) | ((b.z & 255) << 16) | ((uint32_t)(b.w & 255) << 24);
    int2 pk;
    pk.x = (int)lo;
    pk.y = (int)hi;
    *reinterpret_cast<int2*>(w8 + i) = pk;
}

// ---------------------------------------------------------------------------
// Kernel 1: per-token symmetric int8 quantization — wave-per-row.
// ---------------------------------------------------------------------------
__global__ __launch_bounds__(256) void quant_kernel(const float* __restrict__ x,
                                                    int8_t* __restrict__ q,
                                                    float* __restrict__ a_s) {
    const int lane = threadIdx.x & 63;
    const int wid = threadIdx.x >> 6;
    const int row = blockIdx.x * 4 + wid;

    const float4* xv = reinterpret_cast<const float4*>(x + (size_t)row * K_DIM);
    float4 v[8];
    #pragma unroll
    for (int j = 0; j < 8; ++j) v[j] = xv[lane + 64 * j];

    float m = 0.0f;
    #pragma unroll
    for (int j = 0; j < 8; ++j) {
        m = fmaxf(m, fmaxf(fmaxf(fabsf(v[j].x), fabsf(v[j].y)),
                           fmaxf(fabsf(v[j].z), fabsf(v[j].w))));
    }
    #pragma unroll
    for (int off = 32; off > 0; off >>= 1)
        m = fmaxf(m, __shfl_xor(m, off));
    const float mag = m;

    const float inv = (mag == 0.0f) ? 1.0f : (127.0f / mag);

    uint32_t* qo = reinterpret_cast<uint32_t*>(q + (size_t)row * K_DIM);
    #pragma unroll
    for (int j = 0; j < 8; ++j) {
        float e[4] = {v[j].x, v[j].y, v[j].z, v[j].w};
        uint32_t pk = 0;
        #pragma unroll
        for (int c = 0; c < 4; ++c) {
            float d = e[c] * inv;
            d = fminf(fmaxf(d, -128.0f), 127.0f);
            int qi = (int)rintf(d);
            pk |= ((uint32_t)(qi & 255)) << (8 * c);
        }
        qo[lane + 64 * j] = pk;
    }

    if (lane == 0) a_s[row] = (mag == 0.0f) ? 1.0f : (mag / 127.0f);
}

// ---------------------------------------------------------------------------
// Kernel 2: int8 GEMM — m201-style phase schedule ported to i8.
// 256x256, 8 waves (2Mx4N, wave 128x64), 4-deep LDS, 4 phases/iter:
//   P0: ds_read A-half0+B(tile t)   | stage half0(t+2) |           BAR lgkm0 16 MFMA
//   P1: ds_read A-half1(tile t)     | stage half1(t+2) | vmcnt(4)  BAR lgkm0 16 MFMA
//   P2: ds_read A-half0+B(tile t+1) | stage half0(t+3) |           BAR lgkm0 16 MFMA
//   P3: ds_read A-half1(tile t+1)   | stage half1(t+3) | vmcnt(4)  BAR lgkm0 16 MFMA
// vmcnt(4)-then-barrier: P1 guarantees tile t+1 (read at P2), P3 guarantees
// tile t+2 (read next-iter P0). Never drains to 0 mid-loop. Single barrier
// per phase bounds wave skew to one phase -> ds_read rides under MFMA.
// ---------------------------------------------------------------------------
__global__ __launch_bounds__(512, 2) void gemm_i8_kernel(
    const int8_t* __restrict__ A,    // [M, K]
    const int8_t* __restrict__ W,    // [N, K]
    const float* __restrict__ a_s,   // [M]
    const float* __restrict__ w_s,   // [N]
    float* __restrict__ out)         // [M, N]
{
    extern __shared__ int8_t smem[];

    const int t = threadIdx.x;
    const int lane = t & 63;
    const int wid = t >> 6;      // 0..7
    const int wr = wid >> 2;     // 0..1  (M half, 128 rows)
    const int wc = wid & 3;      // 0..3  (N quarter, 64 cols)

    // XCD-aware bijective swizzle (nwg = 512, divisible by 8)
    const int bid = blockIdx.x;
    const int sbid = (bid & 7) * (gridDim.x >> 3) + (bid >> 3);
    const int bm = sbid >> 3;    // 0..63
    const int bn = sbid & 7;     // 0..7

    const int8_t* aSrc = A + (size_t)(bm * BM) * K_DIM;
    const int8_t* bSrc = W + (size_t)(bn * BN) * K_DIM;

    // staging addressing: half-tile = 128 rows A + 128 rows B, 2 loads/thread
    const int rloc = t >> 2;                 // 0..127 row within half
    const int uch = t & 3;                   // 16B chunk within 64B row
    const int swzu = ((uch ^ ((rloc >> 1) & 3)) << 4);   // T2 source pre-swizzle
    const size_t HROW = (size_t)128 * K_DIM;

    #define STAGE_HALF(tl, h)                                                               \
    do {                                                                                    \
        int8_t* base_ = smem + ((tl) & 3) * BUF_BYTES + (h) * 8192;                         \
        const size_t gr_ = (size_t)(tl) * BK + (h) * HROW + (size_t)rloc * K_DIM + swzu;    \
        __builtin_amdgcn_global_load_lds(                                                   \
            (const __attribute__((address_space(1))) void*)(aSrc + gr_),                    \
            (__attribute__((address_space(3))) void*)(base_ + t * 16), 16, 0, 0);           \
        __builtin_amdgcn_global_load_lds(                                                   \
            (const __attribute__((address_space(1))) void*)(bSrc + gr_),                    \
            (__attribute__((address_space(3))) void*)(base_ + HALF_A + t * 16), 16, 0, 0);  \
    } while (0)

    // fragment read addressing (T2-swizzled; +16/+64 rows keep swizzle key)
    const int frow = lane & 15;
    const int fc = lane >> 4;                       // 16B k-chunk 0..3
    const int rA = wr * 128 + frow;
    const int rB = wc * 64 + frow;
    const int aOff = rA * 64 + ((((rA >> 1) & 3) ^ fc) << 4);
    const int bOff = HALF_A + rB * 64 + ((((rB >> 1) & 3) ^ fc) << 4);

    #define LGKM0_FENCE()                                               \
    do {                                                                \
        asm volatile("s_waitcnt lgkmcnt(0)" ::: "memory");              \
        __builtin_amdgcn_sched_barrier(0);                              \
    } while (0)

    v4i acc[8][4] = {};

    // prologue: stage tiles 0,1 (8 loads); ensure tile 0 landed (tile 1's 4 remain)
    STAGE_HALF(0, 0);
    STAGE_HALF(0, 1);
    STAGE_HALF(1, 0);
    STAGE_HALF(1, 1);
    asm volatile("s_waitcnt vmcnt(4)" ::: "memory");
    __builtin_amdgcn_s_barrier();
    asm volatile("" ::: "memory");

    for (int i = 0; i < NT / 2; ++i) {
        const int t0 = 2 * i;
        const bool pf = (t0 + 2 < NT);
        const int8_t* B0 = smem + (t0 & 3) * BUF_BYTES;
        const int8_t* B1 = smem + ((t0 + 1) & 3) * BUF_BYTES;

        v4i af[4], bf[4];

        // -------- P0: tile t0, m-half 0 --------
        #pragma unroll
        for (int mf = 0; mf < 4; ++mf) af[mf] = *(const v4i*)(B0 + aOff + mf * 1024);
        #pragma unroll
        for (int nf = 0; nf < 4; ++nf) bf[nf] = *(const v4i*)(B0 + bOff + nf * 1024);
        if (pf) STAGE_HALF(t0 + 2, 0);
        __builtin_amdgcn_s_barrier();
        LGKM0_FENCE();
        __builtin_amdgcn_s_setprio(1);
        #pragma unroll
        for (int mf = 0; mf < 4; ++mf)
            #pragma unroll
            for (int nf = 0; nf < 4; ++nf)
                acc[mf][nf] = __builtin_amdgcn_mfma_i32_16x16x64_i8(af[mf], bf[nf], acc[mf][nf], 0, 0, 0);
        __builtin_amdgcn_s_setprio(0);

        // -------- P1: tile t0, m-half 1 --------
        #pragma unroll
        for (int mf = 0; mf < 4; ++mf) af[mf] = *(const v4i*)(B0 + aOff + 4096 + mf * 1024);
        if (pf) STAGE_HALF(t0 + 2, 1);
        if (pf) asm volatile("s_waitcnt vmcnt(4)" ::: "memory");
        else    asm volatile("s_waitcnt vmcnt(0)" ::: "memory");
        __builtin_amdgcn_s_barrier();
        LGKM0_FENCE();
        __builtin_amdgcn_s_setprio(1);
        #pragma unroll
        for (int mf = 0; mf < 4; ++mf)
            #pragma unroll
            for (int nf = 0; nf < 4; ++nf)
                acc[mf + 4][nf] = __builtin_amdgcn_mfma_i32_16x16x64_i8(af[mf], bf[nf], acc[mf + 4][nf], 0, 0, 0);
        __builtin_amdgcn_s_setprio(0);

        // -------- P2: tile t0+1, m-half 0 --------
        #pragma unroll
        for (int mf = 0; mf < 4; ++mf) af[mf] = *(const v4i*)(B1 + aOff + mf * 1024);
        #pragma unroll
        for (int nf = 0; nf < 4; ++nf) bf[nf] = *(const v4i*)(B1 + bOff + nf * 1024);
        if (pf) STAGE_HALF(t0 + 3, 0);
        __builtin_amdgcn_s_barrier();
        LGKM0_FENCE();
        __builtin_amdgcn_s_setprio(1);
        #pragma unroll
        for (int mf = 0; mf < 4; ++mf)
            #pragma unroll
            for (int nf = 0; nf < 4; ++nf)
                acc[mf][nf] = __builtin_amdgcn_mfma_i32_16x16x64_i8(af[mf], bf[nf], acc[mf][nf], 0, 0, 0);
        __builtin_amdgcn_s_setprio(0);

        // -------- P3: tile t0+1, m-half 1 --------
        #pragma unroll
        for (int mf = 0; mf < 4; ++mf) af[mf] = *(const v4i*)(B1 + aOff + 4096 + mf * 1024);
        if (pf) STAGE_HALF(t0 + 3, 1);
        if (pf) {
            asm volatile("s_waitcnt vmcnt(4)" ::: "memory");
            __builtin_amdgcn_s_barrier();
        }
        LGKM0_FENCE();
        __builtin_amdgcn_s_setprio(1);
        #pragma unroll
        for (int mf = 0; mf < 4; ++mf)
            #pragma unroll
            for (int nf = 0; nf < 4; ++nf)
                acc[mf + 4][nf] = __builtin_amdgcn_mfma_i32_16x16x64_i8(af[mf], bf[nf], acc[mf + 4][nf], 0, 0, 0);
        __builtin_amdgcn_s_setprio(0);
    }
    #undef STAGE_HALF
    #undef LGKM0_FENCE

    // epilogue: dequant + store. C/D layout: col=lane&15, row=(lane>>4)*4+j [m89]
    const int row0 = bm * BM + wr * 128;
    const int col0 = bn * BN + wc * 64;
    #pragma unroll
    for (int mf = 0; mf < 8; ++mf) {
        const int rbase = row0 + mf * 16 + (lane >> 4) * 4;
        #pragma unroll
        for (int nf = 0; nf < 4; ++nf) {
            const int c = col0 + nf * 16 + (lane & 15);
            const float ws = w_s[c];
            #pragma unroll
            for (int j = 0; j < 4; ++j) {
                const int r = rbase + j;
                out[(size_t)r * N_DIM + c] = ((float)acc[mf][nf][j] * a_s[r]) * ws;
            }
        }
    }
}

// ---------------------------------------------------------------------------
extern "C" void kernel_launch(void* const* d_in, const int* in_sizes, int n_in,
                              void* d_out, int out_size, void* d_ws, size_t ws_size,
                              hipStream_t stream) {
    const float* x = (const float*)d_in[0];
    const int* w32 = (const int*)d_in[1];       // int8 widened to int32 by harness
    const float* wscale = (const float*)d_in[2];
    float* out = (float*)d_out;

    // workspace layout: [ q int8 M*K | a_s f32 M | w8 int8 N*K ]
    int8_t* q = (int8_t*)d_ws;
    float* a_s = (float*)((char*)d_ws + (size_t)M_DIM * K_DIM);
    int8_t* w8 = (int8_t*)((char*)d_ws + (size_t)M_DIM * K_DIM + (size_t)M_DIM * 4);

    hipFuncSetAttribute(reinterpret_cast<const void*>(&gemm_i8_kernel),
                        hipFuncAttributeMaxDynamicSharedMemorySize, SMEM_BYTES);

    pack_w_kernel<<<(N_DIM * K_DIM) / (256 * 8), 256, 0, stream>>>(w32, w8);
    quant_kernel<<<M_DIM / 4, 256, 0, stream>>>(x, q, a_s);

    const int grid = (M_DIM / BM) * (N_DIM / BN);   // 64 * 8 = 512
    gemm_i8_kernel<<<grid, 512, SMEM_BYTES, stream>>>(q, w8, a_s, wscale, out);
}